// Round 1
// baseline (953.848 us; speedup 1.0000x reference)
//
#include <hip/hip_runtime.h>
#include <hip/hip_bf16.h>

typedef __hip_bfloat16 bf16;
typedef __attribute__((ext_vector_type(8))) short short8;
typedef __attribute__((ext_vector_type(4))) float f32x4;

#define BM 128
#define BN 128
#define BK 64

// ---------------------------------------------------------------------------
// async global->LDS, 16B per lane (wave-uniform LDS base + lane*16 implicit)
// ---------------------------------------------------------------------------
__device__ __forceinline__ void gload16(const bf16* g, bf16* l) {
    __builtin_amdgcn_global_load_lds(
        (__attribute__((address_space(1))) void*)g,
        (__attribute__((address_space(3))) void*)l,
        16, 0, 0);
}

// ---------------------------------------------------------------------------
// C = A * B^T (+bias) (+leaky_relu), bf16 inputs, fp32 accum.
// A: [M,K] row-major, B: [N,K] row-major ("bt"), C: [M,N] (bf16 or f32).
// Tile 128x128, 4 waves (2x2 of 64x64), BK=64, mfma_f32_16x16x32_bf16.
// M % 128 == 0, N % 128 == 0, K % 64 == 0 required.
// blockIdx.z = batch index; sA/sB/sC are element batch strides.
// ---------------------------------------------------------------------------
template<int OUT_BF16, int ACT, int HAS_BIAS>
__global__ __launch_bounds__(256, 2)
void gemm_bt(const bf16* __restrict__ Abase, const bf16* __restrict__ Bbase,
             void* __restrict__ Cbase, const float* __restrict__ bias,
             int M, int N, int K,
             long long sA, long long sB, long long sC)
{
    __shared__ bf16 lA[BM * BK];
    __shared__ bf16 lB[BN * BK];

    const int tid  = threadIdx.x;
    const int wid  = tid >> 6;
    const int lane = tid & 63;
    const int wr   = wid >> 1;    // wave row (0..1) -> 64-row subtile
    const int wc   = wid & 1;     // wave col (0..1) -> 64-col subtile

    const long long bz = blockIdx.z;
    const bf16* A = Abase + bz * sA;
    const bf16* B = Bbase + bz * sB;

    const int brow = blockIdx.y * BM;
    const int bcol = blockIdx.x * BN;

    f32x4 acc[4][4] = {};

    // staging geometry: per wave 4 chunks of 1KB for A and B each.
    // chunk q = wid*4+c covers rows q*8..q*8+7 of the tile (row-major [128][64]).
    const int r_in = lane >> 3;        // 0..7 row within chunk
    const int c_in = (lane & 7) * 8;   // col within BK (8 bf16 = 16B)

    const int nK = K / BK;
    for (int kt = 0; kt < nK; ++kt) {
        const int k0 = kt * BK;
        #pragma unroll
        for (int c = 0; c < 4; ++c) {
            const int row = wid * 32 + c * 8 + r_in;
            gload16(A + (long long)(brow + row) * K + (k0 + c_in),
                    &lA[(wid * 4 + c) * 512]);
            gload16(B + (long long)(bcol + row) * K + (k0 + c_in),
                    &lB[(wid * 4 + c) * 512]);
        }
        __syncthreads();   // vmcnt(0) drain + barrier: staged data visible
        #pragma unroll
        for (int kk = 0; kk < 2; ++kk) {
            short8 af[4], bfr[4];
            const int kb = kk * 32 + (lane >> 4) * 8;
            #pragma unroll
            for (int i = 0; i < 4; ++i) {
                af[i]  = *(const short8*)&lA[(wr * 64 + i * 16 + (lane & 15)) * BK + kb];
                bfr[i] = *(const short8*)&lB[(wc * 64 + i * 16 + (lane & 15)) * BK + kb];
            }
            #pragma unroll
            for (int i = 0; i < 4; ++i)
                #pragma unroll
                for (int j = 0; j < 4; ++j)
                    acc[i][j] = __builtin_amdgcn_mfma_f32_16x16x32_bf16(
                        af[i], bfr[j], acc[i][j], 0, 0, 0);
        }
        __syncthreads();   // compute done before next stage overwrites
    }

    // epilogue: C/D layout col = lane&15, row = (lane>>4)*4 + r  [m89]
    const int colb = bcol + wc * 64 + (lane & 15);
    const int rowb = brow + wr * 64 + ((lane >> 4) << 2);
    #pragma unroll
    for (int i = 0; i < 4; ++i) {
        #pragma unroll
        for (int j = 0; j < 4; ++j) {
            const int cc = colb + j * 16;
            float bvv = HAS_BIAS ? bias[cc] : 0.0f;
            #pragma unroll
            for (int r = 0; r < 4; ++r) {
                float vv = acc[i][j][r] + bvv;
                if (ACT) vv = vv > 0.0f ? vv : 0.2f * vv;
                const long long cidx = bz * sC + (long long)(rowb + i * 16 + r) * N + cc;
                if (OUT_BF16) ((bf16*)Cbase)[cidx] = (bf16)vv;
                else          ((float*)Cbase)[cidx] = vv;
            }
        }
    }
}

// ---------------------------------------------------------------------------
// concat(x, emb) -> bf16 [32768, 1152], cols >=1056 zero-padded
// ---------------------------------------------------------------------------
__global__ void concat_cast_kernel(const float* __restrict__ x,
                                   const float* __restrict__ emb,
                                   bf16* __restrict__ out)
{
    const int m = blockIdx.x;          // 0..32767 (b*512+s)
    const int s = m & 511;
    const float* xr = x + (long long)m * 1024;
    bf16* orow = out + (long long)m * 1152;
    for (int c = threadIdx.x; c < 1152; c += 256) {
        float v;
        if (c < 1024)      v = xr[c];
        else if (c < 1056) v = emb[s * 32 + (c - 1024)];
        else               v = 0.0f;
        orow[c] = (bf16)v;
    }
}

// ---------------------------------------------------------------------------
// weight transpose-cast: w [KIN,NIN] f32 row-major -> wt [NP,KP] bf16 (zero pad)
// ---------------------------------------------------------------------------
__global__ void wtrans_kernel(const float* __restrict__ w, bf16* __restrict__ wt,
                              int KIN, int NIN, int KP, int NP)
{
    __shared__ float t[32][33];
    const int k0 = blockIdx.x * 32, n0 = blockIdx.y * 32;
    const int tx = threadIdx.x, ty = threadIdx.y;
    const int kk = k0 + ty, nn = n0 + tx;
    t[ty][tx] = (kk < KIN && nn < NIN) ? w[(long long)kk * NIN + nn] : 0.0f;
    __syncthreads();
    const int ko = k0 + tx, no = n0 + ty;
    if (no < NP && ko < KP)
        wt[(long long)no * KP + ko] = (bf16)t[tx][ty];
}

__global__ void biaspad_kernel(const float* __restrict__ b, float* __restrict__ bp,
                               int n, int np)
{
    int i = blockIdx.x * 256 + threadIdx.x;
    if (i < np) bp[i] = (i < n) ? b[i] : 0.0f;
}

// ---------------------------------------------------------------------------
// batched bf16 transpose: v [64][512][1152] -> vT [64][1152][512]
// ---------------------------------------------------------------------------
__global__ void vtrans_kernel(const bf16* __restrict__ v, bf16* __restrict__ vt)
{
    __shared__ bf16 t[32][33];
    const long long b = blockIdx.z;
    const bf16* vb = v + b * (512LL * 1152);
    bf16* vtb = vt + b * (1152LL * 512);
    const int d0 = blockIdx.x * 32, s0 = blockIdx.y * 32;
    const int tx = threadIdx.x, ty = threadIdx.y;
    t[ty][tx] = vb[(long long)(s0 + ty) * 1152 + d0 + tx];
    __syncthreads();
    vtb[(long long)(d0 + ty) * 512 + s0 + tx] = t[tx][ty];
}

// ---------------------------------------------------------------------------
// row softmax: energy f32 [32768,512] -> attn bf16 [32768,512]; 1 wave / row
// ---------------------------------------------------------------------------
__global__ __launch_bounds__(256)
void softmax_kernel(const float* __restrict__ e, bf16* __restrict__ p)
{
    const int wid = threadIdx.x >> 6, lane = threadIdx.x & 63;
    const long long row = (long long)blockIdx.x * 4 + wid;
    const float* er = e + row * 512;
    float v[8];
    float mx = -3.0e38f;
    #pragma unroll
    for (int j = 0; j < 8; ++j) { v[j] = er[j * 64 + lane]; mx = fmaxf(mx, v[j]); }
    #pragma unroll
    for (int s = 32; s > 0; s >>= 1) mx = fmaxf(mx, __shfl_xor(mx, s));
    float sum = 0.0f;
    #pragma unroll
    for (int j = 0; j < 8; ++j) { v[j] = __expf(v[j] - mx); sum += v[j]; }
    #pragma unroll
    for (int s = 32; s > 0; s >>= 1) sum += __shfl_xor(sum, s);
    const float inv = 1.0f / sum;
    bf16* pr = p + row * 512;
    #pragma unroll
    for (int j = 0; j < 8; ++j) pr[j * 64 + lane] = (bf16)(v[j] * inv);
}

// ---------------------------------------------------------------------------
extern "C" void kernel_launch(void* const* d_in, const int* in_sizes, int n_in,
                              void* d_out, int out_size, void* d_ws, size_t ws_size,
                              hipStream_t stream)
{
    const float* x   = (const float*)d_in[0];
    const float* emb = (const float*)d_in[1];
    const float* w1  = (const float*)d_in[2];
    const float* b1  = (const float*)d_in[3];
    const float* wq  = (const float*)d_in[4];
    const float* bq  = (const float*)d_in[5];
    const float* wk  = (const float*)d_in[6];
    const float* bk  = (const float*)d_in[7];
    const float* wv  = (const float*)d_in[8];
    const float* bv  = (const float*)d_in[9];
    const float* w2  = (const float*)d_in[10];
    const float* b2  = (const float*)d_in[11];
    float* out = (float*)d_out;

    const long long Mrows = 32768;   // 64 * 512
    const int P = 1152;              // padded feature dim (1056 -> 9*128)

    char* ws = (char*)d_ws;
    size_t off = 0;
    auto alloc = [&](size_t bytes) -> char* {
        char* p = ws + off;
        off += (bytes + 255) & ~(size_t)255;
        return p;
    };
    const size_t BIG = (size_t)Mrows * P * 2;           // 75.5 MB each
    bf16* hcat = (bf16*)alloc(BIG);                     // later: vT
    bf16* h    = (bf16*)alloc(BIG);                     // later: energy (f32, 64MB)
    bf16* qb   = (bf16*)alloc(BIG);                     // later: pv
    bf16* kb   = (bf16*)alloc(BIG);
    bf16* vb   = (bf16*)alloc(BIG);                     // later: attn
    bf16* w1T  = (bf16*)alloc((size_t)P * P * 2);
    bf16* wqT  = (bf16*)alloc((size_t)P * P * 2);
    bf16* wkT  = (bf16*)alloc((size_t)P * P * 2);
    bf16* wvT  = (bf16*)alloc((size_t)P * P * 2);
    bf16* w2T  = (bf16*)alloc((size_t)1024 * P * 2);
    float* b1p = (float*)alloc((size_t)P * 4);
    float* bqp = (float*)alloc((size_t)P * 4);
    float* bkp = (float*)alloc((size_t)P * 4);
    float* bvp = (float*)alloc((size_t)P * 4);
    float* b2p = (float*)alloc((size_t)1024 * 4);

    bf16*  vT     = hcat;          // reuse: hcat dead after l1
    float* energy = (float*)h;     // reuse: h dead after v
    bf16*  attn   = vb;            // reuse: v dead after vT
    bf16*  pv     = qb;            // reuse: q dead after energy

    dim3 tb(32, 32);

    concat_cast_kernel<<<32768, 256, 0, stream>>>(x, emb, hcat);
    wtrans_kernel<<<dim3(36, 36), tb, 0, stream>>>(w1, w1T, 1056, 1056, P, P);
    wtrans_kernel<<<dim3(36, 36), tb, 0, stream>>>(wq, wqT, 1056, 1056, P, P);
    wtrans_kernel<<<dim3(36, 36), tb, 0, stream>>>(wk, wkT, 1056, 1056, P, P);
    wtrans_kernel<<<dim3(36, 36), tb, 0, stream>>>(wv, wvT, 1056, 1056, P, P);
    wtrans_kernel<<<dim3(36, 32), tb, 0, stream>>>(w2, w2T, 1056, 1024, P, 1024);
    biaspad_kernel<<<5, 256, 0, stream>>>(b1, b1p, 1056, P);
    biaspad_kernel<<<5, 256, 0, stream>>>(bq, bqp, 1056, P);
    biaspad_kernel<<<5, 256, 0, stream>>>(bk, bkp, 1056, P);
    biaspad_kernel<<<5, 256, 0, stream>>>(bv, bvp, 1056, P);
    biaspad_kernel<<<4, 256, 0, stream>>>(b2, b2p, 1024, 1024);

    // h = leaky_relu(hcat @ w1 + b1)
    gemm_bt<1, 1, 1><<<dim3(P / BN, Mrows / BM, 1), 256, 0, stream>>>(
        hcat, w1T, h, b1p, (int)Mrows, P, P, 0, 0, 0);
    // q, k, v
    gemm_bt<1, 0, 1><<<dim3(P / BN, Mrows / BM, 1), 256, 0, stream>>>(
        h, wqT, qb, bqp, (int)Mrows, P, P, 0, 0, 0);
    gemm_bt<1, 0, 1><<<dim3(P / BN, Mrows / BM, 1), 256, 0, stream>>>(
        h, wkT, kb, bkp, (int)Mrows, P, P, 0, 0, 0);
    gemm_bt<1, 0, 1><<<dim3(P / BN, Mrows / BM, 1), 256, 0, stream>>>(
        h, wvT, vb, bvp, (int)Mrows, P, P, 0, 0, 0);
    // vT
    vtrans_kernel<<<dim3(36, 16, 64), tb, 0, stream>>>(vb, vT);
    // energy[b] = q_b @ k_b^T   (f32 out)
    gemm_bt<0, 0, 0><<<dim3(512 / BN, 512 / BM, 64), 256, 0, stream>>>(
        qb, kb, energy, nullptr, 512, 512, P,
        512LL * P, 512LL * P, 512LL * 512);
    // softmax rows -> bf16
    softmax_kernel<<<8192, 256, 0, stream>>>(energy, attn);
    // pv[b] = attn_b @ v_b  (via vT, bt layout)
    gemm_bt<1, 0, 0><<<dim3(P / BN, 512 / BM, 64), 256, 0, stream>>>(
        attn, vT, pv, nullptr, 512, P, 512,
        512LL * 512, (long long)P * 512, 512LL * P);
    // out = pv @ w2 + b2  (f32 out)
    gemm_bt<0, 0, 1><<<dim3(1024 / BN, Mrows / BM, 1), 256, 0, stream>>>(
        pv, w2T, out, b2p, (int)Mrows, 1024, P, 0, 0, 0);
}

// Round 2
// 806.381 us; speedup vs baseline: 1.1829x; 1.1829x over previous
//
#include <hip/hip_runtime.h>
#include <hip/hip_bf16.h>

typedef __hip_bfloat16 bf16;
typedef __attribute__((ext_vector_type(8))) short short8;
typedef __attribute__((ext_vector_type(4))) float f32x4;

#define BM 128
#define BN 128
#define BK 64

// ---------------------------------------------------------------------------
// async global->LDS, 16B per lane (wave-uniform LDS base + lane*16 implicit)
// ---------------------------------------------------------------------------
__device__ __forceinline__ void gload16(const bf16* g, bf16* l) {
    __builtin_amdgcn_global_load_lds(
        (__attribute__((address_space(1))) void*)g,
        (__attribute__((address_space(3))) void*)l,
        16, 0, 0);
}

// ---------------------------------------------------------------------------
// C = A * B^T (+bias) (+leaky_relu), bf16 in, fp32 accum, m97 128x128 structure.
// A: [M,K] rows stride lda, B: [N,K] rows stride ldb, C rows stride ldc.
// SEG: N split into 1152-wide segments routed to separate buffers
//      (seg s base = Cbase + s*segStride elements), bias indexed by global col.
// XCD-bijective chunk swizzle (T1/m204) over the full 3D linear block id.
// ---------------------------------------------------------------------------
template<int OUT_BF16, int ACT, int HAS_BIAS, int SEG>
__global__ __launch_bounds__(256, 2)
void gemm_bt(const bf16* __restrict__ Abase, const bf16* __restrict__ Bbase,
             void* __restrict__ Cbase, const float* __restrict__ bias,
             int M, int N, int K, int lda, int ldb, int ldc,
             long long sA, long long sB, long long sC, long long segStride)
{
    __shared__ bf16 lA[BM * BK];
    __shared__ bf16 lB[BN * BK];

    // ---- XCD-aware bijective swizzle: contiguous chunk of work per XCD ----
    const int gx = gridDim.x, gy = gridDim.y, gz = gridDim.z;
    {   // silence unused warnings in some paths
        (void)gz;
    }
    const int nwg = gx * gy * gridDim.z;
    int lin = blockIdx.x + gx * (blockIdx.y + gy * blockIdx.z);
    const int qch = nwg >> 3, rch = nwg & 7;
    const int xcd = lin & 7, pos = lin >> 3;
    int nl = (xcd < rch ? xcd * (qch + 1) : rch * (qch + 1) + (xcd - rch) * qch) + pos;
    const int bz = nl / (gx * gy);
    const int rem = nl - bz * (gx * gy);
    const int by = rem / gx;
    const int bx = rem - by * gx;

    const int tid  = threadIdx.x;
    const int wid  = tid >> 6;
    const int lane = tid & 63;
    const int wr   = wid >> 1;
    const int wc   = wid & 1;

    const bf16* A = Abase + (long long)bz * sA;
    const bf16* B = Bbase + (long long)bz * sB;

    const int brow = by * BM;
    const int bcol = bx * BN;

    f32x4 acc[4][4] = {};

    const int r_in = lane >> 3;        // 0..7 row within 8-row chunk
    const int c_in = (lane & 7) * 8;   // col within BK (8 bf16 = 16B)

    const int nK = K / BK;
    for (int kt = 0; kt < nK; ++kt) {
        const int k0 = kt * BK;
        #pragma unroll
        for (int c = 0; c < 4; ++c) {
            const int row = wid * 32 + c * 8 + r_in;
            gload16(A + (long long)(brow + row) * lda + (k0 + c_in),
                    &lA[(wid * 4 + c) * 512]);
            gload16(B + (long long)(bcol + row) * ldb + (k0 + c_in),
                    &lB[(wid * 4 + c) * 512]);
        }
        __syncthreads();
        #pragma unroll
        for (int kk = 0; kk < 2; ++kk) {
            short8 af[4], bfr[4];
            const int kb = kk * 32 + (lane >> 4) * 8;
            #pragma unroll
            for (int i = 0; i < 4; ++i) {
                af[i]  = *(const short8*)&lA[(wr * 64 + i * 16 + (lane & 15)) * BK + kb];
                bfr[i] = *(const short8*)&lB[(wc * 64 + i * 16 + (lane & 15)) * BK + kb];
            }
            #pragma unroll
            for (int i = 0; i < 4; ++i)
                #pragma unroll
                for (int j = 0; j < 4; ++j)
                    acc[i][j] = __builtin_amdgcn_mfma_f32_16x16x32_bf16(
                        af[i], bfr[j], acc[i][j], 0, 0, 0);
        }
        __syncthreads();
    }

    // epilogue: C/D layout col = lane&15, row = (lane>>4)*4 + r  [m89]
    const int colb = bcol + wc * 64 + (lane & 15);
    const int rowb = brow + wr * 64 + ((lane >> 4) << 2);
    int seg = 0;
    long long cofs = (long long)bz * sC;
    if (SEG) { seg = bcol / 1152; cofs += (long long)seg * segStride; }
    #pragma unroll
    for (int i = 0; i < 4; ++i) {
        #pragma unroll
        for (int j = 0; j < 4; ++j) {
            const int gc = colb + j * 16;              // global col (bias idx)
            const int lc = SEG ? gc - seg * 1152 : gc; // col within segment
            float bvv = HAS_BIAS ? bias[gc] : 0.0f;
            #pragma unroll
            for (int r = 0; r < 4; ++r) {
                float vv = acc[i][j][r] + bvv;
                if (ACT) vv = vv > 0.0f ? vv : 0.2f * vv;
                const long long cidx = cofs + (long long)(rowb + i * 16 + r) * ldc + lc;
                if (OUT_BF16) ((bf16*)Cbase)[cidx] = (bf16)vv;
                else          ((float*)Cbase)[cidx] = vv;
            }
        }
    }
}

// ---------------------------------------------------------------------------
// concat(x, emb) -> bf16 [32768, 1152], cols >=1056 zero-padded (vectorized)
// ---------------------------------------------------------------------------
__global__ void concat_cast_kernel(const float* __restrict__ x,
                                   const float* __restrict__ emb,
                                   bf16* __restrict__ out)
{
    const int m = blockIdx.x;          // 0..32767 (b*512+s)
    const int s = m & 511;
    const float* xr = x + (long long)m * 1024;
    bf16* orow = out + (long long)m * 1152;
    for (int g = threadIdx.x; g < 288; g += 256) {
        const int c = g * 4;
        float4 v;
        if (c < 1024)      v = *(const float4*)&xr[c];
        else if (c < 1056) v = *(const float4*)&emb[s * 32 + (c - 1024)];
        else               v = make_float4(0.f, 0.f, 0.f, 0.f);
        bf16 t[4] = { (bf16)v.x, (bf16)v.y, (bf16)v.z, (bf16)v.w };
        *(ushort4*)&orow[c] = *(ushort4*)t;
    }
}

// ---------------------------------------------------------------------------
// weight transpose-cast: w [KIN,NIN] f32 row-major -> wt [NP,KP] bf16 (zero pad)
// ---------------------------------------------------------------------------
__global__ void wtrans_kernel(const float* __restrict__ w, bf16* __restrict__ wt,
                              int KIN, int NIN, int KP, int NP)
{
    __shared__ float t[32][33];
    const int k0 = blockIdx.x * 32, n0 = blockIdx.y * 32;
    const int tx = threadIdx.x, ty = threadIdx.y;
    const int kk = k0 + ty, nn = n0 + tx;
    t[ty][tx] = (kk < KIN && nn < NIN) ? w[(long long)kk * NIN + nn] : 0.0f;
    __syncthreads();
    const int ko = k0 + tx, no = n0 + ty;
    if (no < NP && ko < KP)
        wt[(long long)no * KP + ko] = (bf16)t[tx][ty];
}

__global__ void biaspad_kernel(const float* __restrict__ b, float* __restrict__ bp,
                               int n, int np)
{
    int i = blockIdx.x * 256 + threadIdx.x;
    if (i < np) bp[i] = (i < n) ? b[i] : 0.0f;
}

// ---------------------------------------------------------------------------
// batched bf16 transpose: v [64][512][1152] -> vT [64][1152][512], 64x64 tiles,
// ushort4-vectorized both sides through padded LDS.
// ---------------------------------------------------------------------------
__global__ void vtrans_kernel(const bf16* __restrict__ v, bf16* __restrict__ vt)
{
    __shared__ bf16 t[64][72];
    const long long b = blockIdx.z;
    const bf16* vb = v + b * (512LL * 1152);
    bf16* vtb = vt + b * (1152LL * 512);
    const int d0 = blockIdx.x * 64, s0 = blockIdx.y * 64;
    const int tx = threadIdx.x & 15, ty = threadIdx.x >> 4;   // 16x16
    #pragma unroll
    for (int i = 0; i < 4; ++i) {
        const int row = ty + i * 16;  // s within tile
        *(ushort4*)&t[row][tx * 4] =
            *(const ushort4*)&vb[(long long)(s0 + row) * 1152 + d0 + tx * 4];
    }
    __syncthreads();
    #pragma unroll
    for (int i = 0; i < 4; ++i) {
        const int d = ty + i * 16;    // d within tile
        ushort4 o;
        o.x = *(const ushort*)&t[tx * 4 + 0][d];
        o.y = *(const ushort*)&t[tx * 4 + 1][d];
        o.z = *(const ushort*)&t[tx * 4 + 2][d];
        o.w = *(const ushort*)&t[tx * 4 + 3][d];
        *(ushort4*)&vtb[(long long)(d0 + d) * 512 + s0 + tx * 4] = o;
    }
}

// ---------------------------------------------------------------------------
// row softmax: energy f32 [32768,512] -> attn bf16 [32768,512]; 1 wave / row
// ---------------------------------------------------------------------------
__global__ __launch_bounds__(256)
void softmax_kernel(const float* __restrict__ e, bf16* __restrict__ p)
{
    const int wid = threadIdx.x >> 6, lane = threadIdx.x & 63;
    const long long row = (long long)blockIdx.x * 4 + wid;
    const float* er = e + row * 512;
    float v[8];
    float mx = -3.0e38f;
    #pragma unroll
    for (int j = 0; j < 8; ++j) { v[j] = er[j * 64 + lane]; mx = fmaxf(mx, v[j]); }
    #pragma unroll
    for (int s = 32; s > 0; s >>= 1) mx = fmaxf(mx, __shfl_xor(mx, s));
    float sum = 0.0f;
    #pragma unroll
    for (int j = 0; j < 8; ++j) { v[j] = __expf(v[j] - mx); sum += v[j]; }
    #pragma unroll
    for (int s = 32; s > 0; s >>= 1) sum += __shfl_xor(sum, s);
    const float inv = 1.0f / sum;
    bf16* pr = p + row * 512;
    #pragma unroll
    for (int j = 0; j < 8; ++j) pr[j * 64 + lane] = (bf16)(v[j] * inv);
}

// ---------------------------------------------------------------------------
extern "C" void kernel_launch(void* const* d_in, const int* in_sizes, int n_in,
                              void* d_out, int out_size, void* d_ws, size_t ws_size,
                              hipStream_t stream)
{
    const float* x   = (const float*)d_in[0];
    const float* emb = (const float*)d_in[1];
    const float* w1  = (const float*)d_in[2];
    const float* b1  = (const float*)d_in[3];
    const float* wq  = (const float*)d_in[4];
    const float* bq  = (const float*)d_in[5];
    const float* wk  = (const float*)d_in[6];
    const float* bk  = (const float*)d_in[7];
    const float* wv  = (const float*)d_in[8];
    const float* bv  = (const float*)d_in[9];
    const float* w2  = (const float*)d_in[10];
    const float* b2  = (const float*)d_in[11];
    float* out = (float*)d_out;

    const long long Mrows = 32768;   // 64 * 512
    const int P = 1152;              // padded feature dim (1056 -> 9*128)

    char* ws = (char*)d_ws;
    size_t off = 0;
    auto alloc = [&](size_t bytes) -> char* {
        char* p = ws + off;
        off += (bytes + 255) & ~(size_t)255;
        return p;
    };
    const size_t BIG = (size_t)Mrows * P * 2;            // 75.5 MB
    bf16* hcat   = (bf16*)alloc(BIG);                    // later: vT
    bf16* h      = (bf16*)alloc(BIG);                    // later: energy (f32 64MB)
    bf16* qkv    = (bf16*)alloc(3 * BIG);                // q | k | v slices
    bf16* w1T    = (bf16*)alloc((size_t)P * P * 2);
    bf16* wqkvT  = (bf16*)alloc((size_t)3 * P * P * 2);  // wq|wk|wv rows
    bf16* w2T    = (bf16*)alloc((size_t)1024 * P * 2);
    float* b1p   = (float*)alloc((size_t)P * 4);
    float* bqkv  = (float*)alloc((size_t)3 * P * 4);
    float* b2p   = (float*)alloc((size_t)1024 * 4);

    bf16*  qb     = qkv;
    bf16*  kb     = qkv + Mrows * P;
    bf16*  vb     = qkv + 2 * Mrows * P;
    bf16*  vT     = hcat;            // hcat dead after l1
    float* energy = (float*)h;       // h dead after qkv
    bf16*  attn   = kb;              // k dead after energy
    bf16*  pv     = qb;              // q dead after energy

    dim3 tb(32, 32);

    concat_cast_kernel<<<32768, 256, 0, stream>>>(x, emb, hcat);
    wtrans_kernel<<<dim3(36, 36), tb, 0, stream>>>(w1, w1T, 1056, 1056, P, P);
    wtrans_kernel<<<dim3(36, 36), tb, 0, stream>>>(wq, wqkvT, 1056, 1056, P, P);
    wtrans_kernel<<<dim3(36, 36), tb, 0, stream>>>(wk, wqkvT + (size_t)P * P, 1056, 1056, P, P);
    wtrans_kernel<<<dim3(36, 36), tb, 0, stream>>>(wv, wqkvT + (size_t)2 * P * P, 1056, 1056, P, P);
    wtrans_kernel<<<dim3(36, 32), tb, 0, stream>>>(w2, w2T, 1056, 1024, P, 1024);
    biaspad_kernel<<<5, 256, 0, stream>>>(b1, b1p, 1056, P);
    biaspad_kernel<<<5, 256, 0, stream>>>(bq, bqkv, 1056, P);
    biaspad_kernel<<<5, 256, 0, stream>>>(bk, bqkv + P, 1056, P);
    biaspad_kernel<<<5, 256, 0, stream>>>(bv, bqkv + 2 * P, 1056, P);
    biaspad_kernel<<<4, 256, 0, stream>>>(b2, b2p, 1024, 1024);

    // h = leaky_relu(hcat @ w1 + b1)
    gemm_bt<1, 1, 1, 0><<<dim3(P / BN, Mrows / BM, 1), 256, 0, stream>>>(
        hcat, w1T, h, b1p, (int)Mrows, P, P, P, P, P, 0, 0, 0, 0);
    // fused q|k|v = h @ [wq|wk|wv]^T + [bq|bk|bv]  (N = 3456, segmented out)
    gemm_bt<1, 0, 1, 1><<<dim3(3 * P / BN, Mrows / BM, 1), 256, 0, stream>>>(
        h, wqkvT, qkv, bqkv, (int)Mrows, 3 * P, P, P, P, P, 0, 0, 0,
        (long long)Mrows * P);
    // vT (into dead hcat)
    vtrans_kernel<<<dim3(18, 8, 64), 256, 0, stream>>>(vb, vT);
    // energy[b] = q_b @ k_b^T   (f32, into dead h)
    gemm_bt<0, 0, 0, 0><<<dim3(512 / BN, 512 / BM, 64), 256, 0, stream>>>(
        qb, kb, energy, nullptr, 512, 512, P, P, P, 512,
        512LL * P, 512LL * P, 512LL * 512, 0);
    // softmax rows -> bf16 (into dead k)
    softmax_kernel<<<8192, 256, 0, stream>>>(energy, attn);
    // pv[b] = attn_b @ v_b  (via vT; into dead q)
    gemm_bt<1, 0, 0, 0><<<dim3(P / BN, 512 / BM, 64), 256, 0, stream>>>(
        attn, vT, pv, nullptr, 512, P, 512, 512, 512, P,
        512LL * 512, (long long)P * 512, 512LL * P, 0);
    // out = pv @ w2 + b2  (f32)
    gemm_bt<0, 0, 1, 0><<<dim3(1024 / BN, Mrows / BM, 1), 256, 0, stream>>>(
        pv, w2T, out, b2p, (int)Mrows, 1024, P, P, P, 1024, 0, 0, 0, 0);
}

// Round 3
// 740.776 us; speedup vs baseline: 1.2876x; 1.0886x over previous
//
#include <hip/hip_runtime.h>
#include <hip/hip_bf16.h>

typedef __hip_bfloat16 bf16;
typedef __attribute__((ext_vector_type(8))) short short8;
typedef __attribute__((ext_vector_type(4))) float f32x4;

// ---------------------------------------------------------------------------
// async global->LDS, 16B/lane (wave-uniform LDS base + lane*16 implicit)
// ---------------------------------------------------------------------------
__device__ __forceinline__ void gload16(const bf16* g, bf16* l) {
    __builtin_amdgcn_global_load_lds(
        (__attribute__((address_space(1))) void*)g,
        (__attribute__((address_space(3))) void*)l, 16, 0, 0);
}
#define LGKM0 asm volatile("s_waitcnt lgkmcnt(0)" ::: "memory")
#define VMC(n) asm volatile("s_waitcnt vmcnt(" #n ")" ::: "memory")
__device__ __forceinline__ void bar() {
    asm volatile("" ::: "memory");
    __builtin_amdgcn_s_barrier();
    asm volatile("" ::: "memory");
}

// ---------------------------------------------------------------------------
// stage one half-tile [128 rows x 64 cols bf16] of operand G (row0 = global
// first row, k0 = first col) into LDS region (linear). Source is pre-swizzled:
// LDS(r, slot) = G(r, slot ^ (r&7))  [16B slots], so swizzled ds_reads are
// conflict-free while global_load_lds writes linearly (rule #21).
// Per wave: 2 instructions (q=0,1), rows q*64 + w*8 + (lane>>3), slot lane&7.
// ---------------------------------------------------------------------------
__device__ __forceinline__ void stage_half(const bf16* __restrict__ G, int ld,
                                           int row0, int k0, bf16* lregion,
                                           int w, int lrow, int lslot)
{
    const bf16* s0 = G + (long long)(row0 + w * 8 + lrow) * ld + (k0 + lslot * 8);
    gload16(s0, lregion + (w * 64) * 8);
    gload16(s0 + (long long)64 * ld, lregion + (512 + w * 64) * 8);
}

// ---------------------------------------------------------------------------
// 256x256 8-phase bf16 GEMM, C = A*B^T (+bias)(+leakyrelu).
// A [M,K] lda, B [N,K] ldb (row-major), C [M,N] ldc. M,N %256==0, K%64==0.
// 8 waves (2M x 4N), per-wave C = 128x64, acc[2][2][4][2] f32x4 = 128 VGPR.
// LDS 128KiB: [buf2][op2][half2][128*64]. Counted vmcnt(4) at K-tile
// boundaries only; per-phase: ds_read quadrant | stage 1 half | bar |
// setprio(1) 16xMFMA setprio(0) | lgkm0 | bar.   (T2+T3+T4+T5)
// ---------------------------------------------------------------------------
#define LOAD_A(mh) do { _Pragma("unroll") for (int i_ = 0; i_ < 4; ++i_) { \
    _Pragma("unroll") for (int ks_ = 0; ks_ < 2; ++ks_) \
      aF[i_][ks_] = *(const short8*)(pa + ((mh) * 64 + i_ * 16 + l15) * 64 \
                                        + (((ks_ * 4 + lq) ^ l7) * 8)); } } while (0)
#define LOAD_B(nh, dst) do { _Pragma("unroll") for (int j_ = 0; j_ < 2; ++j_) { \
    _Pragma("unroll") for (int ks_ = 0; ks_ < 2; ++ks_) \
      dst[j_][ks_] = *(const short8*)(pb + (bhr + (nh) * 32 + j_ * 16 + l15) * 64 \
                                         + (((ks_ * 4 + lq) ^ l7) * 8)); } } while (0)
#define DO_Q(mh, nh, BF) do { \
    __builtin_amdgcn_s_setprio(1); \
    _Pragma("unroll") for (int i_ = 0; i_ < 4; ++i_) \
      _Pragma("unroll") for (int j_ = 0; j_ < 2; ++j_) \
        _Pragma("unroll") for (int ks_ = 0; ks_ < 2; ++ks_) \
          acc[mh][nh][i_][j_] = __builtin_amdgcn_mfma_f32_16x16x32_bf16( \
              aF[i_][ks_], BF[j_][ks_], acc[mh][nh][i_][j_], 0, 0, 0); \
    __builtin_amdgcn_s_setprio(0); \
} while (0)

template<int OUT_BF16, int ACT, int HAS_BIAS, int SEGW>
__global__ __launch_bounds__(512, 2)
void gemm256(const bf16* __restrict__ Abase, const bf16* __restrict__ Bbase,
             void* __restrict__ Cbase, const float* __restrict__ bias,
             int K, int lda, int ldb, int ldc,
             long long sA, long long sB, long long sC, long long segStride)
{
    __shared__ bf16 lds[2][2][2][8192];   // 128 KiB

    // XCD-bijective chunk swizzle over the 3D linear block id (T1/m204)
    const int gx = gridDim.x, gy = gridDim.y;
    const int nwg = gx * gy * gridDim.z;
    const int lin = blockIdx.x + gx * (blockIdx.y + gy * blockIdx.z);
    const int qch = nwg >> 3, rch = nwg & 7;
    const int xcd = lin & 7, pos = lin >> 3;
    const int nl = (xcd < rch ? xcd * (qch + 1)
                              : rch * (qch + 1) + (xcd - rch) * qch) + pos;
    const int bz = nl / (gx * gy);
    const int rem = nl - bz * (gx * gy);
    const int by = rem / gx;
    const int bx = rem - by * gx;

    const int tid = threadIdx.x;
    const int wid = tid >> 6, lane = tid & 63;
    const int wm = wid >> 2, wn = wid & 3;          // 2 x 4 waves
    const int l15 = lane & 15, l7 = lane & 7, lq = lane >> 4;
    const int lrow = lane >> 3, lslot = l7 ^ lrow;  // staging per-lane geom
    const int bhr = (wn & 1) * 64;                  // B row base within half

    const bf16* A = Abase + (long long)bz * sA;
    const bf16* B = Bbase + (long long)bz * sB;
    const int brow = by * 256, bcol = bx * 256;

    f32x4 acc[2][2][4][2] = {};
    short8 aF[4][2], bF0[2][2], bF1[2][2];

    const int nt = K >> 6;

    // ---- prologue: t0.B0,B1 ; t0.A0,A1 -> buf0 ; t1.B0,B1 -> buf1 ----
    stage_half(B, ldb, bcol,       0,  &lds[0][1][0][0], wid, lrow, lslot);
    stage_half(B, ldb, bcol + 128, 0,  &lds[0][1][1][0], wid, lrow, lslot);
    stage_half(A, lda, brow,       0,  &lds[0][0][0][0], wid, lrow, lslot);
    stage_half(A, lda, brow + 128, 0,  &lds[0][0][1][0], wid, lrow, lslot);
    stage_half(B, ldb, bcol,       64, &lds[1][1][0][0], wid, lrow, lslot);
    stage_half(B, ldb, bcol + 128, 64, &lds[1][1][1][0], wid, lrow, lslot);
    VMC(4);
    bar();

    for (int t = 0; t < nt; ++t) {
        const int b = t & 1;
        const bf16* pa = &lds[b][0][wm][0];
        const bf16* pb = &lds[b][1][wn >> 1][0];
        bf16* oA = &lds[b ^ 1][0][0][0];   // next tile's A goes to other buf
        bf16* cB = &lds[b][1][0][0];       // tile t+2's B reuses current buf
        const int t1 = (t + 1 == nt) ? 0 : t + 1;
        const int t2 = (t + 2 >= nt) ? t + 2 - nt : t + 2;
        const int k1 = t1 << 6, k2 = t2 << 6;

        // phase 1: Q(0,0); stage (t+1).A0
        LOAD_A(0); LOAD_B(0, bF0);
        stage_half(A, lda, brow, k1, oA, wid, lrow, lslot);
        bar();
        DO_Q(0, 0, bF0);
        LGKM0; bar();

        // phase 2: Q(0,1); stage (t+1).A1
        LOAD_B(1, bF1);
        stage_half(A, lda, brow + 128, k1, oA + 8192, wid, lrow, lslot);
        bar();
        DO_Q(0, 1, bF1);
        LGKM0; bar();

        // phase 3: Q(1,1); stage (t+2).B0 (B0 region dead after phase 2)
        LOAD_A(1);
        stage_half(B, ldb, bcol, k2, cB, wid, lrow, lslot);
        bar();
        DO_Q(1, 1, bF1);
        LGKM0; bar();

        // phase 4: Q(1,0); stage (t+2).B1 ; counted vmcnt at tile boundary
        stage_half(B, ldb, bcol + 128, k2, cB + 8192, wid, lrow, lslot);
        bar();
        DO_Q(1, 0, bF0);
        VMC(4);
        bar();
    }
    VMC(0);   // drain wrapped stray stages before LDS is released

    // ---- epilogue: C/D layout col = lane&15, row = (lane>>4)*4 + rr ----
    int seg = 0;
    long long cofs = (long long)bz * sC;
    if (SEGW) { seg = bcol / SEGW; cofs += (long long)seg * segStride; }
    #pragma unroll
    for (int mh = 0; mh < 2; ++mh)
      #pragma unroll
      for (int nh = 0; nh < 2; ++nh)
        #pragma unroll
        for (int i = 0; i < 4; ++i)
          #pragma unroll
          for (int j = 0; j < 2; ++j) {
              const int gc = bcol + wn * 64 + nh * 32 + j * 16 + l15;
              const int lc = SEGW ? gc - seg * SEGW : gc;
              const int row0 = brow + wm * 128 + mh * 64 + i * 16 + lq * 4;
              float bvv = HAS_BIAS ? bias[gc] : 0.0f;
              #pragma unroll
              for (int rr = 0; rr < 4; ++rr) {
                  float vv = acc[mh][nh][i][j][rr] + bvv;
                  if (ACT) vv = vv > 0.0f ? vv : 0.2f * vv;
                  const long long cidx = cofs + (long long)(row0 + rr) * ldc + lc;
                  if (OUT_BF16) ((bf16*)Cbase)[cidx] = (bf16)vv;
                  else          ((float*)Cbase)[cidx] = vv;
              }
          }
}

// ---------------------------------------------------------------------------
// concat(x, emb) -> bf16 [32768, 1152], cols >=1056 zero-padded
// ---------------------------------------------------------------------------
__global__ void concat_cast_kernel(const float* __restrict__ x,
                                   const float* __restrict__ emb,
                                   bf16* __restrict__ out)
{
    const int m = blockIdx.x;
    const int s = m & 511;
    const float* xr = x + (long long)m * 1024;
    bf16* orow = out + (long long)m * 1152;
    for (int g = threadIdx.x; g < 288; g += 256) {
        const int c = g * 4;
        float4 v;
        if (c < 1024)      v = *(const float4*)&xr[c];
        else if (c < 1056) v = *(const float4*)&emb[s * 32 + (c - 1024)];
        else               v = make_float4(0.f, 0.f, 0.f, 0.f);
        bf16 t[4] = { (bf16)v.x, (bf16)v.y, (bf16)v.z, (bf16)v.w };
        *(ushort4*)&orow[c] = *(ushort4*)t;
    }
}

// ---------------------------------------------------------------------------
// weight transpose-cast: w [KIN,NIN] f32 -> wt [NP,KP] bf16 (zero pad)
// ---------------------------------------------------------------------------
__global__ void wtrans_kernel(const float* __restrict__ w, bf16* __restrict__ wt,
                              int KIN, int NIN, int KP, int NP)
{
    __shared__ float t[32][33];
    const int k0 = blockIdx.x * 32, n0 = blockIdx.y * 32;
    const int tx = threadIdx.x, ty = threadIdx.y;
    const int kk = k0 + ty, nn = n0 + tx;
    t[ty][tx] = (kk < KIN && nn < NIN) ? w[(long long)kk * NIN + nn] : 0.0f;
    __syncthreads();
    const int ko = k0 + tx, no = n0 + ty;
    if (no < NP && ko < KP)
        wt[(long long)no * KP + ko] = (bf16)t[tx][ty];
}

__global__ void biaspad_kernel(const float* __restrict__ b, float* __restrict__ bp,
                               int n, int np)
{
    int i = blockIdx.x * 256 + threadIdx.x;
    if (i < np) bp[i] = (i < n) ? b[i] : 0.0f;
}

// ---------------------------------------------------------------------------
// batched bf16 transpose: v [64][512][1280] -> vT [64][1280][512]
// ---------------------------------------------------------------------------
__global__ void vtrans_kernel(const bf16* __restrict__ v, bf16* __restrict__ vt)
{
    __shared__ bf16 t[64][72];
    const long long b = blockIdx.z;
    const bf16* vb = v + b * (512LL * 1280);
    bf16* vtb = vt + b * (1280LL * 512);
    const int d0 = blockIdx.x * 64, s0 = blockIdx.y * 64;
    const int tx = threadIdx.x & 15, ty = threadIdx.x >> 4;   // 16x16
    #pragma unroll
    for (int i = 0; i < 4; ++i) {
        const int row = ty + i * 16;
        *(ushort4*)&t[row][tx * 4] =
            *(const ushort4*)&vb[(long long)(s0 + row) * 1280 + d0 + tx * 4];
    }
    __syncthreads();
    #pragma unroll
    for (int i = 0; i < 4; ++i) {
        const int d = ty + i * 16;
        ushort4 o;
        o.x = *(const ushort*)&t[tx * 4 + 0][d];
        o.y = *(const ushort*)&t[tx * 4 + 1][d];
        o.z = *(const ushort*)&t[tx * 4 + 2][d];
        o.w = *(const ushort*)&t[tx * 4 + 3][d];
        *(ushort4*)&vtb[(long long)(d0 + d) * 512 + s0 + tx * 4] = o;
    }
}

// ---------------------------------------------------------------------------
// row softmax: energy f32 [32768,512] -> attn bf16 [32768,512]; 1 wave/row
// ---------------------------------------------------------------------------
__global__ __launch_bounds__(256)
void softmax_kernel(const float* __restrict__ e, bf16* __restrict__ p)
{
    const int wid = threadIdx.x >> 6, lane = threadIdx.x & 63;
    const long long row = (long long)blockIdx.x * 4 + wid;
    const float* er = e + row * 512;
    float v[8];
    float mx = -3.0e38f;
    #pragma unroll
    for (int j = 0; j < 8; ++j) { v[j] = er[j * 64 + lane]; mx = fmaxf(mx, v[j]); }
    #pragma unroll
    for (int s = 32; s > 0; s >>= 1) mx = fmaxf(mx, __shfl_xor(mx, s));
    float sum = 0.0f;
    #pragma unroll
    for (int j = 0; j < 8; ++j) { v[j] = __expf(v[j] - mx); sum += v[j]; }
    #pragma unroll
    for (int s = 32; s > 0; s >>= 1) sum += __shfl_xor(sum, s);
    const float inv = 1.0f / sum;
    bf16* pr = p + row * 512;
    #pragma unroll
    for (int j = 0; j < 8; ++j) pr[j * 64 + lane] = (bf16)(v[j] * inv);
}

// ---------------------------------------------------------------------------
extern "C" void kernel_launch(void* const* d_in, const int* in_sizes, int n_in,
                              void* d_out, int out_size, void* d_ws, size_t ws_size,
                              hipStream_t stream)
{
    const float* x   = (const float*)d_in[0];
    const float* emb = (const float*)d_in[1];
    const float* w1  = (const float*)d_in[2];
    const float* b1  = (const float*)d_in[3];
    const float* wq  = (const float*)d_in[4];
    const float* bq  = (const float*)d_in[5];
    const float* wk  = (const float*)d_in[6];
    const float* bk  = (const float*)d_in[7];
    const float* wv  = (const float*)d_in[8];
    const float* bv  = (const float*)d_in[9];
    const float* w2  = (const float*)d_in[10];
    const float* b2  = (const float*)d_in[11];
    float* out = (float*)d_out;

    const long long Mrows = 32768;   // 64 * 512
    const int PK = 1152;             // concat K-pad (1056 -> 18*64)
    const int P  = 1280;             // feature pad for 256-divisible N (5*256)

    char* ws = (char*)d_ws;
    size_t off = 0;
    auto alloc = [&](size_t bytes) -> char* {
        char* p = ws + off;
        off += (bytes + 255) & ~(size_t)255;
        return p;
    };
    bf16* hcat  = (bf16*)alloc((size_t)Mrows * PK * 2);       // 75.5 MB
    bf16* h     = (bf16*)alloc((size_t)Mrows * P * 2);        // 83.9 MB
    bf16* qkv   = (bf16*)alloc((size_t)3 * Mrows * P * 2);    // 251.7 MB
    bf16* w1T   = (bf16*)alloc((size_t)P * PK * 2);
    bf16* wqkvT = (bf16*)alloc((size_t)3 * P * P * 2);
    bf16* w2T   = (bf16*)alloc((size_t)1024 * P * 2);
    float* b1p  = (float*)alloc((size_t)P * 4);
    float* bqkv = (float*)alloc((size_t)3 * P * 4);
    float* b2p  = (float*)alloc((size_t)1024 * 4);

    bf16*  qb     = qkv;
    bf16*  kb     = qkv + Mrows * P;
    bf16*  vb     = qkv + 2 * Mrows * P;
    bf16*  vT     = h;               // h dead after qkv
    float* energy = (float*)hcat;    // hcat dead after l1 (67.1 <= 75.5 MB)
    bf16*  attn   = kb;              // k dead after energy
    bf16*  pv     = qb;              // q dead after energy

    dim3 tb(32, 32);

    concat_cast_kernel<<<32768, 256, 0, stream>>>(x, emb, hcat);
    wtrans_kernel<<<dim3(36, 40), tb, 0, stream>>>(w1, w1T, 1056, 1056, PK, P);
    wtrans_kernel<<<dim3(40, 40), tb, 0, stream>>>(wq, wqkvT, 1056, 1056, P, P);
    wtrans_kernel<<<dim3(40, 40), tb, 0, stream>>>(wk, wqkvT + (size_t)P * P, 1056, 1056, P, P);
    wtrans_kernel<<<dim3(40, 40), tb, 0, stream>>>(wv, wqkvT + (size_t)2 * P * P, 1056, 1056, P, P);
    wtrans_kernel<<<dim3(40, 32), tb, 0, stream>>>(w2, w2T, 1056, 1024, P, 1024);
    biaspad_kernel<<<5, 256, 0, stream>>>(b1, b1p, 1056, P);
    biaspad_kernel<<<5, 256, 0, stream>>>(bq, bqkv, 1056, P);
    biaspad_kernel<<<5, 256, 0, stream>>>(bk, bqkv + P, 1056, P);
    biaspad_kernel<<<5, 256, 0, stream>>>(bv, bqkv + 2 * P, 1056, P);
    biaspad_kernel<<<4, 256, 0, stream>>>(b2, b2p, 1024, 1024);

    // h = leaky_relu(hcat @ w1 + b1)            M=32768 N=1280 K=1152
    gemm256<1, 1, 1, 0><<<dim3(P / 256, Mrows / 256, 1), 512, 0, stream>>>(
        hcat, w1T, h, b1p, PK, PK, PK, P, 0, 0, 0, 0);
    // q|k|v = h @ [wq|wk|wv]^T + bias           M=32768 N=3840 K=1280
    gemm256<1, 0, 1, 1280><<<dim3(3 * P / 256, Mrows / 256, 1), 512, 0, stream>>>(
        h, wqkvT, qkv, bqkv, P, P, P, P, 0, 0, 0, (long long)Mrows * P);
    // vT (into dead h)
    vtrans_kernel<<<dim3(20, 8, 64), 256, 0, stream>>>(vb, vT);
    // energy[b] = q_b @ k_b^T  (f32, into dead hcat)   512x512xK1280 x64
    gemm256<0, 0, 0, 0><<<dim3(2, 2, 64), 512, 0, stream>>>(
        qb, kb, energy, nullptr, P, P, P, 512,
        512LL * P, 512LL * P, 512LL * 512, 0);
    // softmax rows -> bf16 (into dead k)
    softmax_kernel<<<8192, 256, 0, stream>>>(energy, attn);
    // pv[b] = attn_b @ v_b (via vT; into dead q)       512x1280xK512 x64
    gemm256<1, 0, 0, 0><<<dim3(5, 2, 64), 512, 0, stream>>>(
        attn, vT, pv, nullptr, 512, 512, 512, P,
        512LL * 512, (long long)P * 512, 512LL * P, 0);
    // out = pv @ w2 + b2  (f32)                        M=32768 N=1024 K=1280
    gemm256<0, 0, 1, 0><<<dim3(1024 / 256, Mrows / 256, 1), 512, 0, stream>>>(
        pv, w2T, out, b2p, P, P, P, 1024, 0, 0, 0, 0);
}

// Round 4
// 692.083 us; speedup vs baseline: 1.3782x; 1.0704x over previous
//
#include <hip/hip_runtime.h>
#include <hip/hip_bf16.h>
#include <cstdint>

typedef __hip_bfloat16 bf16;
typedef __attribute__((ext_vector_type(8))) short short8;
typedef __attribute__((ext_vector_type(4))) float f32x4;

// ---------------------------------------------------------------------------
// async global->LDS, 16B/lane (wave-uniform LDS base + lane*16 implicit)
// ---------------------------------------------------------------------------
__device__ __forceinline__ void gload16(const bf16* g, bf16* l) {
    __builtin_amdgcn_global_load_lds(
        (__attribute__((address_space(1))) void*)g,
        (__attribute__((address_space(3))) void*)l, 16, 0, 0);
}
#define VMC(n) asm volatile("s_waitcnt vmcnt(" #n ")" ::: "memory")
// counted lgkm wait + sched fence (rule 18: sched_barrier right after)
#define WLG(n) do { asm volatile("s_waitcnt lgkmcnt(" #n ")" ::: "memory"); \
                    __builtin_amdgcn_sched_barrier(0); } while (0)
// inline-asm ds_read_b128 (volatile: order preserved vs other asm)
#define DSR(dst, a, off) \
    asm volatile("ds_read_b128 %0, %1 offset:" off : "=v"(dst) : "v"(a))
__device__ __forceinline__ void bar() {
    asm volatile("" ::: "memory");
    __builtin_amdgcn_s_barrier();
    asm volatile("" ::: "memory");
}

// ---------------------------------------------------------------------------
// stage one half-tile [128 rows x 64 cols bf16] into a linear LDS region.
// Source pre-swizzled: LDS(r, slot) = G(r, slot ^ (r&7)) [16B slots] so the
// swizzled ds_reads are conflict-free while global_load_lds writes linearly.
// ---------------------------------------------------------------------------
__device__ __forceinline__ void stage_half(const bf16* __restrict__ G, int ld,
                                           int row0, int k0, bf16* lregion,
                                           int w, int lrow, int lslot)
{
    const bf16* s0 = G + (long long)(row0 + w * 8 + lrow) * ld + (k0 + lslot * 8);
    gload16(s0, lregion + (w * 64) * 8);
    gload16(s0 + (long long)64 * ld, lregion + (512 + w * 64) * 8);
}

// 2 chained MFMAs (ks=0,1) for accumulator cell (mh,nh,i,j)
#define MM2(mh, nh, i, j, BF) do { \
    acc[mh][nh][i][j] = __builtin_amdgcn_mfma_f32_16x16x32_bf16( \
        aF[i][0], BF[j][0], acc[mh][nh][i][j], 0, 0, 0); \
    acc[mh][nh][i][j] = __builtin_amdgcn_mfma_f32_16x16x32_bf16( \
        aF[i][1], BF[j][1], acc[mh][nh][i][j], 0, 0, 0); \
} while (0)
#define MMI(mh, nh, i, BF) do { MM2(mh, nh, i, 0, BF); MM2(mh, nh, i, 1, BF); } while (0)

// ---------------------------------------------------------------------------
// 256x256 8-phase bf16 GEMM, C = A*B^T (+bias)(+leakyrelu).
// Counted-lgkm ladder: MFMA cluster starts after the first fragment group
// lands and overlaps the remaining ds_read drain (T2+T3+T4+T5 + ladder).
// ---------------------------------------------------------------------------
template<int OUT_BF16, int ACT, int HAS_BIAS, int SEGW>
__global__ __launch_bounds__(512, 2)
void gemm256(const bf16* __restrict__ Abase, const bf16* __restrict__ Bbase,
             void* __restrict__ Cbase, const float* __restrict__ bias,
             int K, int lda, int ldb, int ldc,
             long long sA, long long sB, long long sC, long long segStride)
{
    __shared__ bf16 lds[2][2][2][8192];   // [buf][op][half][128*64], 128 KiB

    // XCD-bijective chunk swizzle (T1/m204) over 3D linear block id
    const int gx = gridDim.x, gy = gridDim.y;
    const int nwg = gx * gy * gridDim.z;
    const int lin = blockIdx.x + gx * (blockIdx.y + gy * blockIdx.z);
    const int qch = nwg >> 3, rch = nwg & 7;
    const int xcd = lin & 7, pos = lin >> 3;
    const int nl = (xcd < rch ? xcd * (qch + 1)
                              : rch * (qch + 1) + (xcd - rch) * qch) + pos;
    const int bz = nl / (gx * gy);
    const int rem = nl - bz * (gx * gy);
    const int by = rem / gx;
    const int bx = rem - by * gx;

    const int tid = threadIdx.x;
    const int wid = tid >> 6, lane = tid & 63;
    const int wm = wid >> 2, wn = wid & 3;          // 2 x 4 waves
    const int l15 = lane & 15, l7 = lane & 7, lq = lane >> 4;
    const int lrow = lane >> 3, lslot = l7 ^ lrow;  // staging per-lane geom

    const bf16* A = Abase + (long long)bz * sA;
    const bf16* B = Bbase + (long long)bz * sB;
    const int brow = by * 256, bcol = bx * 256;

    // swizzled ds_read base addresses: ks toggles ^64, buffer toggles ^0x10000,
    // quadrant/fragment goes into the 16-bit offset: immediate.
    const uint32_t lds0 = (uint32_t)(uintptr_t)
        (__attribute__((address_space(3))) bf16*)&lds[0][0][0][0];
    const uint32_t lanecore = (uint32_t)(l15 * 128 + ((lq ^ (l7 & 3)) * 16)
                                         + ((l7 >> 2) * 64));
    const uint32_t vA0 = lds0 + wm * 16384 + lanecore;
    const uint32_t vB0 = lds0 + 32768 + (wn >> 1) * 16384 + (wn & 1) * 8192
                         + lanecore;

    f32x4 acc[2][2][4][2] = {};
    short8 aF[4][2], bF0[2][2], bF1[2][2];

    const int nt = K >> 6;

    // ---- prologue: t0.B, t0.A -> buf0 ; t1.B -> buf1 ----
    stage_half(B, ldb, bcol,       0,  &lds[0][1][0][0], wid, lrow, lslot);
    stage_half(B, ldb, bcol + 128, 0,  &lds[0][1][1][0], wid, lrow, lslot);
    stage_half(A, lda, brow,       0,  &lds[0][0][0][0], wid, lrow, lslot);
    stage_half(A, lda, brow + 128, 0,  &lds[0][0][1][0], wid, lrow, lslot);
    stage_half(B, ldb, bcol,       64, &lds[1][1][0][0], wid, lrow, lslot);
    stage_half(B, ldb, bcol + 128, 64, &lds[1][1][1][0], wid, lrow, lslot);
    VMC(4);
    bar();

    for (int t = 0; t < nt; ++t) {
        const int b = t & 1;
        const uint32_t bb = ((uint32_t)b) << 16;
        const uint32_t aA = vA0 ^ bb, aA1 = aA ^ 64u;
        const uint32_t aB = vB0 ^ bb, aB1 = aB ^ 64u;
        bf16* oA = &lds[b ^ 1][0][0][0];   // next tile's A -> other buffer
        bf16* cB = &lds[b][1][0][0];       // tile t+2's B -> current buffer
        const int t1 = (t + 1 == nt) ? 0 : t + 1;
        const int t2 = (t + 2 >= nt) ? t + 2 - nt : t + 2;
        const int k1 = t1 << 6, k2 = t2 << 6;

        // ---- phase 1: Q(0,0); reads bF0(4)+aF.mh0(8); stage (t+1).A0 ----
        DSR(bF0[0][0], aB, "0");    DSR(bF0[0][1], aB1, "0");
        DSR(bF0[1][0], aB, "2048"); DSR(bF0[1][1], aB1, "2048");
        DSR(aF[0][0], aA, "0");     DSR(aF[0][1], aA1, "0");
        DSR(aF[1][0], aA, "2048");  DSR(aF[1][1], aA1, "2048");
        DSR(aF[2][0], aA, "4096");  DSR(aF[2][1], aA1, "4096");
        DSR(aF[3][0], aA, "6144");  DSR(aF[3][1], aA1, "6144");
        stage_half(A, lda, brow, k1, oA, wid, lrow, lslot);
        bar();
        __builtin_amdgcn_s_setprio(1);
        WLG(6); MMI(0, 0, 0, bF0);
        WLG(4); MMI(0, 0, 1, bF0);
        WLG(2); MMI(0, 0, 2, bF0);
        WLG(0); MMI(0, 0, 3, bF0);
        __builtin_amdgcn_s_setprio(0);
        bar();

        // ---- phase 2: Q(0,1); reads bF1(4); stage (t+1).A1 ----
        DSR(bF1[0][0], aB, "4096"); DSR(bF1[0][1], aB1, "4096");
        DSR(bF1[1][0], aB, "6144"); DSR(bF1[1][1], aB1, "6144");
        stage_half(A, lda, brow + 128, k1, oA + 8192, wid, lrow, lslot);
        bar();
        __builtin_amdgcn_s_setprio(1);
        WLG(2); MM2(0,1,0,0,bF1); MM2(0,1,1,0,bF1); MM2(0,1,2,0,bF1); MM2(0,1,3,0,bF1);
        WLG(0); MM2(0,1,0,1,bF1); MM2(0,1,1,1,bF1); MM2(0,1,2,1,bF1); MM2(0,1,3,1,bF1);
        __builtin_amdgcn_s_setprio(0);
        bar();

        // ---- phase 3: Q(1,1); reload aF.mh1(8); stage (t+2).B0 ----
        DSR(aF[0][0], aA, "8192");  DSR(aF[0][1], aA1, "8192");
        DSR(aF[1][0], aA, "10240"); DSR(aF[1][1], aA1, "10240");
        DSR(aF[2][0], aA, "12288"); DSR(aF[2][1], aA1, "12288");
        DSR(aF[3][0], aA, "14336"); DSR(aF[3][1], aA1, "14336");
        stage_half(B, ldb, bcol, k2, cB, wid, lrow, lslot);
        bar();
        __builtin_amdgcn_s_setprio(1);
        WLG(6); MMI(1, 1, 0, bF1);
        WLG(4); MMI(1, 1, 1, bF1);
        WLG(2); MMI(1, 1, 2, bF1);
        WLG(0); MMI(1, 1, 3, bF1);
        __builtin_amdgcn_s_setprio(0);
        bar();

        // ---- phase 4: Q(1,0); no reads; stage (t+2).B1; counted vmcnt ----
        stage_half(B, ldb, bcol + 128, k2, cB + 8192, wid, lrow, lslot);
        bar();
        __builtin_amdgcn_s_setprio(1);
        MMI(1, 0, 0, bF0); MMI(1, 0, 1, bF0);
        MMI(1, 0, 2, bF0); MMI(1, 0, 3, bF0);
        __builtin_amdgcn_s_setprio(0);
        VMC(4);
        bar();
    }
    VMC(0);   // drain wrapped stray stages

    // ---- epilogue: C/D layout col = lane&15, row = (lane>>4)*4 + rr ----
    int seg = 0;
    long long cofs = (long long)bz * sC;
    if (SEGW) { seg = bcol / SEGW; cofs += (long long)seg * segStride; }
    #pragma unroll
    for (int mh = 0; mh < 2; ++mh)
      #pragma unroll
      for (int nh = 0; nh < 2; ++nh)
        #pragma unroll
        for (int i = 0; i < 4; ++i)
          #pragma unroll
          for (int j = 0; j < 2; ++j) {
              const int gc = bcol + wn * 64 + nh * 32 + j * 16 + l15;
              const int lc = SEGW ? gc - seg * SEGW : gc;
              const int row0 = brow + wm * 128 + mh * 64 + i * 16 + lq * 4;
              float bvv = HAS_BIAS ? bias[gc] : 0.0f;
              #pragma unroll
              for (int rr = 0; rr < 4; ++rr) {
                  float vv = acc[mh][nh][i][j][rr] + bvv;
                  if (ACT) vv = vv > 0.0f ? vv : 0.2f * vv;
                  const long long cidx = cofs + (long long)(row0 + rr) * ldc + lc;
                  if (OUT_BF16) ((bf16*)Cbase)[cidx] = (bf16)vv;
                  else          ((float*)Cbase)[cidx] = vv;
              }
          }
}

// ---------------------------------------------------------------------------
// concat(x, emb) -> bf16 [32768, 1152], cols >=1056 zero-padded
// ---------------------------------------------------------------------------
__global__ void concat_cast_kernel(const float* __restrict__ x,
                                   const float* __restrict__ emb,
                                   bf16* __restrict__ out)
{
    const int m = blockIdx.x;
    const int s = m & 511;
    const float* xr = x + (long long)m * 1024;
    bf16* orow = out + (long long)m * 1152;
    for (int g = threadIdx.x; g < 288; g += 256) {
        const int c = g * 4;
        float4 v;
        if (c < 1024)      v = *(const float4*)&xr[c];
        else if (c < 1056) v = *(const float4*)&emb[s * 32 + (c - 1024)];
        else               v = make_float4(0.f, 0.f, 0.f, 0.f);
        bf16 t[4] = { (bf16)v.x, (bf16)v.y, (bf16)v.z, (bf16)v.w };
        *(ushort4*)&orow[c] = *(ushort4*)t;
    }
}

// ---------------------------------------------------------------------------
// weight transpose-cast: w [KIN,NIN] f32 -> wt [NP,KP] bf16 (zero pad)
// ---------------------------------------------------------------------------
__global__ void wtrans_kernel(const float* __restrict__ w, bf16* __restrict__ wt,
                              int KIN, int NIN, int KP, int NP)
{
    __shared__ float t[32][33];
    const int k0 = blockIdx.x * 32, n0 = blockIdx.y * 32;
    const int tx = threadIdx.x, ty = threadIdx.y;
    const int kk = k0 + ty, nn = n0 + tx;
    t[ty][tx] = (kk < KIN && nn < NIN) ? w[(long long)kk * NIN + nn] : 0.0f;
    __syncthreads();
    const int ko = k0 + tx, no = n0 + ty;
    if (no < NP && ko < KP)
        wt[(long long)no * KP + ko] = (bf16)t[tx][ty];
}

__global__ void biaspad_kernel(const float* __restrict__ b, float* __restrict__ bp,
                               int n, int np)
{
    int i = blockIdx.x * 256 + threadIdx.x;
    if (i < np) bp[i] = (i < n) ? b[i] : 0.0f;
}

// ---------------------------------------------------------------------------
// batched bf16 transpose: v [64][512][1280] -> vT [64][1280][512]
// ---------------------------------------------------------------------------
__global__ void vtrans_kernel(const bf16* __restrict__ v, bf16* __restrict__ vt)
{
    __shared__ bf16 t[64][72];
    const long long b = blockIdx.z;
    const bf16* vb = v + b * (512LL * 1280);
    bf16* vtb = vt + b * (1280LL * 512);
    const int d0 = blockIdx.x * 64, s0 = blockIdx.y * 64;
    const int tx = threadIdx.x & 15, ty = threadIdx.x >> 4;   // 16x16
    #pragma unroll
    for (int i = 0; i < 4; ++i) {
        const int row = ty + i * 16;
        *(ushort4*)&t[row][tx * 4] =
            *(const ushort4*)&vb[(long long)(s0 + row) * 1280 + d0 + tx * 4];
    }
    __syncthreads();
    #pragma unroll
    for (int i = 0; i < 4; ++i) {
        const int d = ty + i * 16;
        ushort4 o;
        o.x = *(const ushort*)&t[tx * 4 + 0][d];
        o.y = *(const ushort*)&t[tx * 4 + 1][d];
        o.z = *(const ushort*)&t[tx * 4 + 2][d];
        o.w = *(const ushort*)&t[tx * 4 + 3][d];
        *(ushort4*)&vtb[(long long)(d0 + d) * 512 + s0 + tx * 4] = o;
    }
}

// ---------------------------------------------------------------------------
// row softmax: energy f32 [32768,512] -> attn bf16 [32768,512]; 1 wave/row
// ---------------------------------------------------------------------------
__global__ __launch_bounds__(256)
void softmax_kernel(const float* __restrict__ e, bf16* __restrict__ p)
{
    const int wid = threadIdx.x >> 6, lane = threadIdx.x & 63;
    const long long row = (long long)blockIdx.x * 4 + wid;
    const float* er = e + row * 512;
    float v[8];
    float mx = -3.0e38f;
    #pragma unroll
    for (int j = 0; j < 8; ++j) { v[j] = er[j * 64 + lane]; mx = fmaxf(mx, v[j]); }
    #pragma unroll
    for (int s = 32; s > 0; s >>= 1) mx = fmaxf(mx, __shfl_xor(mx, s));
    float sum = 0.0f;
    #pragma unroll
    for (int j = 0; j < 8; ++j) { v[j] = __expf(v[j] - mx); sum += v[j]; }
    #pragma unroll
    for (int s = 32; s > 0; s >>= 1) sum += __shfl_xor(sum, s);
    const float inv = 1.0f / sum;
    bf16* pr = p + row * 512;
    #pragma unroll
    for (int j = 0; j < 8; ++j) pr[j * 64 + lane] = (bf16)(v[j] * inv);
}

// ---------------------------------------------------------------------------
extern "C" void kernel_launch(void* const* d_in, const int* in_sizes, int n_in,
                              void* d_out, int out_size, void* d_ws, size_t ws_size,
                              hipStream_t stream)
{
    const float* x   = (const float*)d_in[0];
    const float* emb = (const float*)d_in[1];
    const float* w1  = (const float*)d_in[2];
    const float* b1  = (const float*)d_in[3];
    const float* wq  = (const float*)d_in[4];
    const float* bq  = (const float*)d_in[5];
    const float* wk  = (const float*)d_in[6];
    const float* bk  = (const float*)d_in[7];
    const float* wv  = (const float*)d_in[8];
    const float* bv  = (const float*)d_in[9];
    const float* w2  = (const float*)d_in[10];
    const float* b2  = (const float*)d_in[11];
    float* out = (float*)d_out;

    const long long Mrows = 32768;   // 64 * 512
    const int PK = 1152;             // concat storage pad (1056 -> 18*64)
    const int P  = 1280;             // feature pad for 256-divisible N (5*256)
    const int KR = 1088;             // reduced K: 17*64 >= 1056 (rest is zeros)

    char* ws = (char*)d_ws;
    size_t off = 0;
    auto alloc = [&](size_t bytes) -> char* {
        char* p = ws + off;
        off += (bytes + 255) & ~(size_t)255;
        return p;
    };
    bf16* hcat  = (bf16*)alloc((size_t)Mrows * PK * 2);       // 75.5 MB
    bf16* h     = (bf16*)alloc((size_t)Mrows * P * 2);        // 83.9 MB
    bf16* qkv   = (bf16*)alloc((size_t)3 * Mrows * P * 2);    // 251.7 MB
    bf16* w1T   = (bf16*)alloc((size_t)P * PK * 2);
    bf16* wqkvT = (bf16*)alloc((size_t)3 * P * P * 2);
    bf16* w2T   = (bf16*)alloc((size_t)1024 * P * 2);
    float* b1p  = (float*)alloc((size_t)P * 4);
    float* bqkv = (float*)alloc((size_t)3 * P * 4);
    float* b2p  = (float*)alloc((size_t)1024 * 4);

    bf16*  qb     = qkv;
    bf16*  kb     = qkv + Mrows * P;
    bf16*  vb     = qkv + 2 * Mrows * P;
    bf16*  vT     = h;               // h dead after qkv
    float* energy = (float*)hcat;    // hcat dead after l1 (67.1 <= 75.5 MB)
    bf16*  attn   = kb;              // k dead after energy
    bf16*  pv     = qb;              // q dead after energy

    dim3 tb(32, 32);

    concat_cast_kernel<<<32768, 256, 0, stream>>>(x, emb, hcat);
    wtrans_kernel<<<dim3(36, 40), tb, 0, stream>>>(w1, w1T, 1056, 1056, PK, P);
    wtrans_kernel<<<dim3(40, 40), tb, 0, stream>>>(wq, wqkvT, 1056, 1056, P, P);
    wtrans_kernel<<<dim3(40, 40), tb, 0, stream>>>(wk, wqkvT + (size_t)P * P, 1056, 1056, P, P);
    wtrans_kernel<<<dim3(40, 40), tb, 0, stream>>>(wv, wqkvT + (size_t)2 * P * P, 1056, 1056, P, P);
    wtrans_kernel<<<dim3(40, 32), tb, 0, stream>>>(w2, w2T, 1056, 1024, P, 1024);
    biaspad_kernel<<<5, 256, 0, stream>>>(b1, b1p, 1056, P);
    biaspad_kernel<<<5, 256, 0, stream>>>(bq, bqkv, 1056, P);
    biaspad_kernel<<<5, 256, 0, stream>>>(bk, bqkv + P, 1056, P);
    biaspad_kernel<<<5, 256, 0, stream>>>(bv, bqkv + 2 * P, 1056, P);
    biaspad_kernel<<<4, 256, 0, stream>>>(b2, b2p, 1024, 1024);

    // h = leaky_relu(hcat @ w1 + b1)            M=32768 N=1280 K=1088
    gemm256<1, 1, 1, 0><<<dim3(P / 256, Mrows / 256, 1), 512, 0, stream>>>(
        hcat, w1T, h, b1p, KR, PK, PK, P, 0, 0, 0, 0);
    // q|k|v = h @ [wq|wk|wv]^T + bias           M=32768 N=3840 K=1088
    gemm256<1, 0, 1, 1280><<<dim3(3 * P / 256, Mrows / 256, 1), 512, 0, stream>>>(
        h, wqkvT, qkv, bqkv, KR, P, P, P, 0, 0, 0, (long long)Mrows * P);
    // vT (into dead h)
    vtrans_kernel<<<dim3(20, 8, 64), 256, 0, stream>>>(vb, vT);
    // energy[b] = q_b @ k_b^T  (f32, into dead hcat)   512x512xK1088 x64
    gemm256<0, 0, 0, 0><<<dim3(2, 2, 64), 512, 0, stream>>>(
        qb, kb, energy, nullptr, KR, P, P, 512,
        512LL * P, 512LL * P, 512LL * 512, 0);
    // softmax rows -> bf16 (into dead k)
    softmax_kernel<<<8192, 256, 0, stream>>>(energy, attn);
    // pv[b] = attn_b @ v_b (via vT; into dead q)       512x1280xK512 x64
    gemm256<1, 0, 0, 0><<<dim3(5, 2, 64), 512, 0, stream>>>(
        attn, vT, pv, nullptr, 512, 512, 512, P,
        512LL * 512, (long long)P * 512, 512LL * P, 0);
    // out = pv @ w2 + b2  (f32)                        M=32768 N=1024 K=1088
    gemm256<0, 0, 1, 0><<<dim3(1024 / 256, Mrows / 256, 1), 512, 0, stream>>>(
        pv, w2T, out, b2p, KR, P, P, 1024, 0, 0, 0, 0);
}

// Round 5
// 671.737 us; speedup vs baseline: 1.4200x; 1.0303x over previous
//
#include <hip/hip_runtime.h>
#include <hip/hip_bf16.h>
#include <cstdint>

typedef __hip_bfloat16 bf16;
typedef __attribute__((ext_vector_type(8))) short short8;
typedef __attribute__((ext_vector_type(4))) float f32x4;

// ---------------------------------------------------------------------------
// async global->LDS, 16B/lane (wave-uniform LDS base + lane*16 implicit)
// ---------------------------------------------------------------------------
__device__ __forceinline__ void gload16(const bf16* g, bf16* l) {
    __builtin_amdgcn_global_load_lds(
        (__attribute__((address_space(1))) void*)g,
        (__attribute__((address_space(3))) void*)l, 16, 0, 0);
}
#define VMC(n) asm volatile("s_waitcnt vmcnt(" #n ")" ::: "memory")
#define WLG(n) do { asm volatile("s_waitcnt lgkmcnt(" #n ")" ::: "memory"); \
                    __builtin_amdgcn_sched_barrier(0); } while (0)
#define DSR(dst, a, off) \
    asm volatile("ds_read_b128 %0, %1 offset:" off : "=v"(dst) : "v"(a))
__device__ __forceinline__ void bar() {
    asm volatile("" ::: "memory");
    __builtin_amdgcn_s_barrier();
    asm volatile("" ::: "memory");
}

// ---------------------------------------------------------------------------
// stage one half-tile [128 rows x 64 cols bf16] into a linear LDS region.
// Source pre-swizzled: LDS(r, slot) = G(r, slot ^ (r&7)) [16B slots] so the
// swizzled ds_reads are conflict-free while global_load_lds writes linearly.
// ---------------------------------------------------------------------------
__device__ __forceinline__ void stage_half(const bf16* __restrict__ G, int ld,
                                           int row0, int k0, bf16* lregion,
                                           int w, int lrow, int lslot)
{
    const bf16* s0 = G + (long long)(row0 + w * 8 + lrow) * ld + (k0 + lslot * 8);
    gload16(s0, lregion + (w * 64) * 8);
    gload16(s0 + (long long)64 * ld, lregion + (512 + w * 64) * 8);
}

#define MM2(mh, nh, i, j, BF) do { \
    acc[mh][nh][i][j] = __builtin_amdgcn_mfma_f32_16x16x32_bf16( \
        aF[i][0], BF[j][0], acc[mh][nh][i][j], 0, 0, 0); \
    acc[mh][nh][i][j] = __builtin_amdgcn_mfma_f32_16x16x32_bf16( \
        aF[i][1], BF[j][1], acc[mh][nh][i][j], 0, 0, 0); \
} while (0)
#define MMI(mh, nh, i, BF) do { MM2(mh, nh, i, 0, BF); MM2(mh, nh, i, 1, BF); } while (0)

// ---------------------------------------------------------------------------
// 256x256 8-phase bf16 GEMM, C = A*B^T (+bias)(+leakyrelu).
// ROUTE: output col gc routes to matrix gc/1152, local col gc%1152
//        (fused q|k|v with total-pad only). Writes guarded by gc < nwrite.
// ---------------------------------------------------------------------------
template<int OUT_BF16, int ACT, int HAS_BIAS, int ROUTE>
__global__ __launch_bounds__(512, 2)
void gemm256(const bf16* __restrict__ Abase, const bf16* __restrict__ Bbase,
             void* __restrict__ Cbase, const float* __restrict__ bias,
             int K, int lda, int ldb, int ldc, int nwrite,
             long long sA, long long sB, long long sC, long long segStride)
{
    __shared__ bf16 lds[2][2][2][8192];   // [buf][op][half][128*64], 128 KiB

    // XCD-bijective chunk swizzle (T1/m204) over 3D linear block id
    const int gx = gridDim.x, gy = gridDim.y;
    const int nwg = gx * gy * gridDim.z;
    const int lin = blockIdx.x + gx * (blockIdx.y + gy * blockIdx.z);
    const int qch = nwg >> 3, rch = nwg & 7;
    const int xcd = lin & 7, pos = lin >> 3;
    const int nl = (xcd < rch ? xcd * (qch + 1)
                              : rch * (qch + 1) + (xcd - rch) * qch) + pos;
    const int bz = nl / (gx * gy);
    const int rem = nl - bz * (gx * gy);
    const int by = rem / gx;
    const int bx = rem - by * gx;

    const int tid = threadIdx.x;
    const int wid = tid >> 6, lane = tid & 63;
    const int wm = wid >> 2, wn = wid & 3;          // 2 x 4 waves
    const int l15 = lane & 15, l7 = lane & 7, lq = lane >> 4;
    const int lrow = lane >> 3, lslot = l7 ^ lrow;  // staging per-lane geom

    const bf16* A = Abase + (long long)bz * sA;
    const bf16* B = Bbase + (long long)bz * sB;
    const int brow = by * 256, bcol = bx * 256;

    // swizzled ds_read bases: ks toggles ^64, buffer toggles ^0x10000,
    // fragment goes in the offset: immediate.
    const uint32_t lds0 = (uint32_t)(uintptr_t)
        (__attribute__((address_space(3))) bf16*)&lds[0][0][0][0];
    const uint32_t lanecore = (uint32_t)(l15 * 128 + ((lq ^ (l7 & 3)) * 16)
                                         + ((l7 >> 2) * 64));
    const uint32_t vA0 = lds0 + wm * 16384 + lanecore;
    const uint32_t vB0 = lds0 + 32768 + (wn >> 1) * 16384 + (wn & 1) * 8192
                         + lanecore;

    f32x4 acc[2][2][4][2] = {};
    short8 aF[4][2], bF0[2][2], bF1[2][2];

    const int nt = K >> 6;

    // ---- prologue: t0.B, t0.A -> buf0 ; t1.B -> buf1 ----
    stage_half(B, ldb, bcol,       0,  &lds[0][1][0][0], wid, lrow, lslot);
    stage_half(B, ldb, bcol + 128, 0,  &lds[0][1][1][0], wid, lrow, lslot);
    stage_half(A, lda, brow,       0,  &lds[0][0][0][0], wid, lrow, lslot);
    stage_half(A, lda, brow + 128, 0,  &lds[0][0][1][0], wid, lrow, lslot);
    stage_half(B, ldb, bcol,       64, &lds[1][1][0][0], wid, lrow, lslot);
    stage_half(B, ldb, bcol + 128, 64, &lds[1][1][1][0], wid, lrow, lslot);
    VMC(4);
    bar();

    for (int t = 0; t < nt; ++t) {
        const int b = t & 1;
        const uint32_t bb = ((uint32_t)b) << 16;
        const uint32_t aA = vA0 ^ bb, aA1 = aA ^ 64u;
        const uint32_t aB = vB0 ^ bb, aB1 = aB ^ 64u;
        bf16* oA = &lds[b ^ 1][0][0][0];   // next tile's A -> other buffer
        bf16* cB = &lds[b][1][0][0];       // tile t+2's B -> current buffer
        const int t1 = (t + 1 == nt) ? 0 : t + 1;
        const int t2 = (t + 2 >= nt) ? t + 2 - nt : t + 2;
        const int k1 = t1 << 6, k2 = t2 << 6;

        // ---- phase 1: Q(0,0); reads bF0(4)+aF.mh0(8); stage (t+1).A0 ----
        DSR(bF0[0][0], aB, "0");    DSR(bF0[0][1], aB1, "0");
        DSR(bF0[1][0], aB, "2048"); DSR(bF0[1][1], aB1, "2048");
        DSR(aF[0][0], aA, "0");     DSR(aF[0][1], aA1, "0");
        DSR(aF[1][0], aA, "2048");  DSR(aF[1][1], aA1, "2048");
        DSR(aF[2][0], aA, "4096");  DSR(aF[2][1], aA1, "4096");
        DSR(aF[3][0], aA, "6144");  DSR(aF[3][1], aA1, "6144");
        stage_half(A, lda, brow, k1, oA, wid, lrow, lslot);
        bar();
        __builtin_amdgcn_s_setprio(1);
        WLG(6); MMI(0, 0, 0, bF0);
        WLG(4); MMI(0, 0, 1, bF0);
        WLG(2); MMI(0, 0, 2, bF0);
        WLG(0); MMI(0, 0, 3, bF0);
        __builtin_amdgcn_s_setprio(0);
        bar();

        // ---- phase 2: Q(0,1); reads bF1(4); stage (t+1).A1 ----
        DSR(bF1[0][0], aB, "4096"); DSR(bF1[0][1], aB1, "4096");
        DSR(bF1[1][0], aB, "6144"); DSR(bF1[1][1], aB1, "6144");
        stage_half(A, lda, brow + 128, k1, oA + 8192, wid, lrow, lslot);
        bar();
        __builtin_amdgcn_s_setprio(1);
        WLG(2); MM2(0,1,0,0,bF1); MM2(0,1,1,0,bF1); MM2(0,1,2,0,bF1); MM2(0,1,3,0,bF1);
        WLG(0); MM2(0,1,0,1,bF1); MM2(0,1,1,1,bF1); MM2(0,1,2,1,bF1); MM2(0,1,3,1,bF1);
        __builtin_amdgcn_s_setprio(0);
        bar();

        // ---- phase 3: Q(1,1); reload aF.mh1(8); stage (t+2).B0 ----
        DSR(aF[0][0], aA, "8192");  DSR(aF[0][1], aA1, "8192");
        DSR(aF[1][0], aA, "10240"); DSR(aF[1][1], aA1, "10240");
        DSR(aF[2][0], aA, "12288"); DSR(aF[2][1], aA1, "12288");
        DSR(aF[3][0], aA, "14336"); DSR(aF[3][1], aA1, "14336");
        stage_half(B, ldb, bcol, k2, cB, wid, lrow, lslot);
        bar();
        __builtin_amdgcn_s_setprio(1);
        WLG(6); MMI(1, 1, 0, bF1);
        WLG(4); MMI(1, 1, 1, bF1);
        WLG(2); MMI(1, 1, 2, bF1);
        WLG(0); MMI(1, 1, 3, bF1);
        __builtin_amdgcn_s_setprio(0);
        bar();

        // ---- phase 4: Q(1,0); no reads; stage (t+2).B1; counted vmcnt ----
        stage_half(B, ldb, bcol + 128, k2, cB + 8192, wid, lrow, lslot);
        bar();
        __builtin_amdgcn_s_setprio(1);
        MMI(1, 0, 0, bF0); MMI(1, 0, 1, bF0);
        MMI(1, 0, 2, bF0); MMI(1, 0, 3, bF0);
        __builtin_amdgcn_s_setprio(0);
        VMC(4);
        bar();
    }
    VMC(0);   // drain wrapped stray stages

    // ---- epilogue: C/D layout col = lane&15, row = (lane>>4)*4 + rr ----
    const long long cofs0 = (long long)bz * sC;
    #pragma unroll
    for (int mh = 0; mh < 2; ++mh)
      #pragma unroll
      for (int nh = 0; nh < 2; ++nh)
        #pragma unroll
        for (int i = 0; i < 4; ++i)
          #pragma unroll
          for (int j = 0; j < 2; ++j) {
              const int gc = bcol + wn * 64 + nh * 32 + j * 16 + l15;
              int lc = gc;
              long long cofs = cofs0;
              if (ROUTE) {
                  const unsigned seg = (unsigned)gc / 1152u;
                  lc = gc - (int)(seg * 1152u);
                  cofs += (long long)seg * segStride;
              }
              const bool wr = gc < nwrite;
              const float bvv = (HAS_BIAS && wr) ? bias[gc] : 0.0f;
              const int row0 = brow + wm * 128 + mh * 64 + i * 16 + lq * 4;
              if (wr) {
                  #pragma unroll
                  for (int rr = 0; rr < 4; ++rr) {
                      float vv = acc[mh][nh][i][j][rr] + bvv;
                      if (ACT) vv = vv > 0.0f ? vv : 0.2f * vv;
                      const long long cidx = cofs + (long long)(row0 + rr) * ldc + lc;
                      if (OUT_BF16) ((bf16*)Cbase)[cidx] = (bf16)vv;
                      else          ((float*)Cbase)[cidx] = vv;
                  }
              }
          }
}

// ---------------------------------------------------------------------------
// concat(x, emb) -> bf16 [32768, 1088]; cols 1024..1055 emb, 1056..1087 zero
// ---------------------------------------------------------------------------
__global__ void concat_cast_kernel(const float* __restrict__ x,
                                   const float* __restrict__ emb,
                                   bf16* __restrict__ out)
{
    const int m = blockIdx.x;
    const int s = m & 511;
    const float* xr = x + (long long)m * 1024;
    bf16* orow = out + (long long)m * 1088;
    for (int g = threadIdx.x; g < 272; g += 256) {
        const int c = g * 4;
        float4 v;
        if (c < 1024)      v = *(const float4*)&xr[c];
        else if (c < 1056) v = *(const float4*)&emb[s * 32 + (c - 1024)];
        else               v = make_float4(0.f, 0.f, 0.f, 0.f);
        bf16 t[4] = { (bf16)v.x, (bf16)v.y, (bf16)v.z, (bf16)v.w };
        *(ushort4*)&orow[c] = *(ushort4*)t;
    }
}

// ---------------------------------------------------------------------------
// batched weight transpose-cast: z picks {w1,wq,wk,wv,w2}; dst [NP][1088] bf16
// (zero-padded outside KIN x NIN). wv segment has NP=1280 to zero wqkvT tail.
// ---------------------------------------------------------------------------
__global__ void wtrans5_kernel(const float* __restrict__ w1, const float* __restrict__ wq,
                               const float* __restrict__ wk, const float* __restrict__ wv,
                               const float* __restrict__ w2,
                               bf16* __restrict__ w1T, bf16* __restrict__ wqkvT,
                               bf16* __restrict__ w2T)
{
    const int z = blockIdx.z;
    const float* src; bf16* dst; int NIN, NP;
    switch (z) {
        case 0: src = w1; dst = w1T;                        NIN = 1056; NP = 1280; break;
        case 1: src = wq; dst = wqkvT;                      NIN = 1056; NP = 1152; break;
        case 2: src = wk; dst = wqkvT + 1152LL * 1088;      NIN = 1056; NP = 1152; break;
        case 3: src = wv; dst = wqkvT + 2304LL * 1088;      NIN = 1056; NP = 1280; break;
        default: src = w2; dst = w2T;                       NIN = 1024; NP = 1024; break;
    }
    const int KIN = 1056, KP = 1088;
    const int k0 = blockIdx.x * 32, n0 = blockIdx.y * 32;
    if (n0 >= NP) return;
    __shared__ float t[32][33];
    const int tx = threadIdx.x, ty = threadIdx.y;
    const int kk = k0 + ty, nn = n0 + tx;
    t[ty][tx] = (kk < KIN && nn < NIN) ? src[(long long)kk * NIN + nn] : 0.0f;
    __syncthreads();
    const int ko = k0 + tx, no = n0 + ty;
    if (no < NP && ko < KP)
        dst[(long long)no * KP + ko] = (bf16)t[tx][ty];
}

// ---------------------------------------------------------------------------
// merged bias prep: b1p[1280], bqkv[3456], b2p[1024]
// ---------------------------------------------------------------------------
__global__ void biasprep_kernel(const float* __restrict__ b1, const float* __restrict__ bq,
                                const float* __restrict__ bk, const float* __restrict__ bv,
                                const float* __restrict__ b2,
                                float* __restrict__ b1p, float* __restrict__ bqkv,
                                float* __restrict__ b2p)
{
    const int i = blockIdx.x * 256 + threadIdx.x;
    if (i < 1280) {
        b1p[i] = (i < 1056) ? b1[i] : 0.0f;
    } else if (i < 1280 + 3456) {
        const int j = i - 1280;
        const int seg = j / 1152, c = j - seg * 1152;
        const float* src = seg == 0 ? bq : (seg == 1 ? bk : bv);
        bqkv[j] = (c < 1056) ? src[c] : 0.0f;
    } else if (i < 1280 + 3456 + 1024) {
        const int j = i - (1280 + 3456);
        b2p[j] = b2[j];
    }
}

// ---------------------------------------------------------------------------
// batched bf16 transpose: v [64][512][1152] -> vT [64][1280][512]
// (vT rows >= 1152 zero-filled)
// ---------------------------------------------------------------------------
__global__ void vtrans_kernel(const bf16* __restrict__ v, bf16* __restrict__ vt)
{
    __shared__ bf16 t[64][72];
    const long long b = blockIdx.z;
    const bf16* vb = v + b * (512LL * 1152);
    bf16* vtb = vt + b * (1280LL * 512);
    const int d0 = blockIdx.x * 64, s0 = blockIdx.y * 64;
    const int tx = threadIdx.x & 15, ty = threadIdx.x >> 4;   // 16x16
    const bool zz = d0 >= 1152;   // 1152 = 18*64, tiles 18,19 are pure pad
    #pragma unroll
    for (int i = 0; i < 4; ++i) {
        const int row = ty + i * 16;
        ushort4 val = make_ushort4(0, 0, 0, 0);
        if (!zz)
            val = *(const ushort4*)&vb[(long long)(s0 + row) * 1152 + d0 + tx * 4];
        *(ushort4*)&t[row][tx * 4] = val;
    }
    __syncthreads();
    #pragma unroll
    for (int i = 0; i < 4; ++i) {
        const int d = ty + i * 16;
        ushort4 o;
        o.x = *(const ushort*)&t[tx * 4 + 0][d];
        o.y = *(const ushort*)&t[tx * 4 + 1][d];
        o.z = *(const ushort*)&t[tx * 4 + 2][d];
        o.w = *(const ushort*)&t[tx * 4 + 3][d];
        *(ushort4*)&vtb[(long long)(d0 + d) * 512 + s0 + tx * 4] = o;
    }
}

// ---------------------------------------------------------------------------
// row softmax: energy f32 [32768,512] -> attn bf16 [32768,512]; 1 wave/row
// ---------------------------------------------------------------------------
__global__ __launch_bounds__(256)
void softmax_kernel(const float* __restrict__ e, bf16* __restrict__ p)
{
    const int wid = threadIdx.x >> 6, lane = threadIdx.x & 63;
    const long long row = (long long)blockIdx.x * 4 + wid;
    const float* er = e + row * 512;
    float v[8];
    float mx = -3.0e38f;
    #pragma unroll
    for (int j = 0; j < 8; ++j) { v[j] = er[j * 64 + lane]; mx = fmaxf(mx, v[j]); }
    #pragma unroll
    for (int s = 32; s > 0; s >>= 1) mx = fmaxf(mx, __shfl_xor(mx, s));
    float sum = 0.0f;
    #pragma unroll
    for (int j = 0; j < 8; ++j) { v[j] = __expf(v[j] - mx); sum += v[j]; }
    #pragma unroll
    for (int s = 32; s > 0; s >>= 1) sum += __shfl_xor(sum, s);
    const float inv = 1.0f / sum;
    bf16* pr = p + row * 512;
    #pragma unroll
    for (int j = 0; j < 8; ++j) pr[j * 64 + lane] = (bf16)(v[j] * inv);
}

// ---------------------------------------------------------------------------
extern "C" void kernel_launch(void* const* d_in, const int* in_sizes, int n_in,
                              void* d_out, int out_size, void* d_ws, size_t ws_size,
                              hipStream_t stream)
{
    const float* x   = (const float*)d_in[0];
    const float* emb = (const float*)d_in[1];
    const float* w1  = (const float*)d_in[2];
    const float* b1  = (const float*)d_in[3];
    const float* wq  = (const float*)d_in[4];
    const float* bq  = (const float*)d_in[5];
    const float* wk  = (const float*)d_in[6];
    const float* bk  = (const float*)d_in[7];
    const float* wv  = (const float*)d_in[8];
    const float* bv  = (const float*)d_in[9];
    const float* w2  = (const float*)d_in[10];
    const float* b2  = (const float*)d_in[11];
    float* out = (float*)d_out;

    const long long Mrows = 32768;   // 64 * 512
    const int KR = 1088;             // compute K (17*64 >= 1056)
    const int WQ = 1152;             // stored width of q/k/v

    char* ws = (char*)d_ws;
    size_t off = 0;
    auto alloc = [&](size_t bytes) -> char* {
        char* p = ws + off;
        off += (bytes + 255) & ~(size_t)255;
        return p;
    };
    char* R1    = alloc((size_t)Mrows * KR * 2);            // hcat / energy / pv
    char* R2    = alloc((size_t)64 * 1280 * 512 * 2);       // h / vT
    bf16* qkv   = (bf16*)alloc((size_t)3 * Mrows * WQ * 2); // q | k | v
    bf16* w1T   = (bf16*)alloc((size_t)1280 * KR * 2);
    bf16* wqkvT = (bf16*)alloc((size_t)3584 * KR * 2);
    bf16* w2T   = (bf16*)alloc((size_t)1024 * KR * 2);
    float* b1p  = (float*)alloc((size_t)1280 * 4);
    float* bqkv = (float*)alloc((size_t)3456 * 4);
    float* b2p  = (float*)alloc((size_t)1024 * 4);

    bf16*  hcat   = (bf16*)R1;
    float* energy = (float*)R1;                 // after l1 consumed hcat
    bf16*  pv     = (bf16*)R1;                  // after softmax consumed energy
    bf16*  h      = (bf16*)R2;
    bf16*  vT     = (bf16*)R2;                  // after qkv consumed h
    bf16*  qb     = qkv;
    bf16*  kb     = qkv + Mrows * WQ;
    bf16*  vb     = qkv + 2 * Mrows * WQ;
    bf16*  attn   = kb;                         // k dead after energy

    concat_cast_kernel<<<32768, 256, 0, stream>>>(x, emb, hcat);
    wtrans5_kernel<<<dim3(34, 40, 5), dim3(32, 32), 0, stream>>>(
        w1, wq, wk, wv, w2, w1T, wqkvT, w2T);
    biasprep_kernel<<<23, 256, 0, stream>>>(b1, bq, bk, bv, b2, b1p, bqkv, b2p);

    // h = leaky_relu(hcat @ w1 + b1)   M=32768 Ngrid=1280 K=1088, store 1088
    gemm256<1, 1, 1, 0><<<dim3(5, 128, 1), 512, 0, stream>>>(
        hcat, w1T, h, b1p, KR, KR, KR, KR, KR, 0, 0, 0, 0);
    // q|k|v = h @ [wq|wk|wv]^T + bias  M=32768 Ngrid=3584 K=1088, route 1152
    gemm256<1, 0, 1, 1><<<dim3(14, 128, 1), 512, 0, stream>>>(
        h, wqkvT, qkv, bqkv, KR, KR, KR, WQ, 3456, 0, 0, 0,
        (long long)Mrows * WQ);
    // vT (into dead h region)
    vtrans_kernel<<<dim3(20, 8, 64), 256, 0, stream>>>(vb, vT);
    // energy[b] = q_b @ k_b^T  (f32, into dead hcat region)
    gemm256<0, 0, 0, 0><<<dim3(2, 2, 64), 512, 0, stream>>>(
        qb, kb, energy, nullptr, KR, WQ, WQ, 512, 512,
        512LL * WQ, 512LL * WQ, 512LL * 512, 0);
    // softmax rows -> bf16 (into dead k region)
    softmax_kernel<<<8192, 256, 0, stream>>>(energy, attn);
    // pv[b] = attn_b @ v_b (via vT; into dead energy region), store 1088
    gemm256<1, 0, 0, 0><<<dim3(5, 2, 64), 512, 0, stream>>>(
        attn, vT, pv, nullptr, 512, 512, 512, KR, KR,
        512LL * 512, 1280LL * 512, 512LL * KR, 0);
    // out = pv @ w2 + b2  (f32)
    gemm256<0, 0, 1, 0><<<dim3(4, 128, 1), 512, 0, stream>>>(
        pv, w2T, out, b2p, KR, KR, KR, 1024, 1024, 0, 0, 0, 0);
}